// Round 6
// baseline (754.333 us; speedup 1.0000x reference)
//
#include <hip/hip_runtime.h>
#include <math.h>

#define IMG_H 512
#define IMG_W 512
#define NIMG 96            // 32 * 3
#define BH 32              // output rows per band
#define NBANDS 16          // 512 / 32
#define ROWS_IN (BH + 10)  // 42 streamed input rows per band
#define NCHUNK 4           // 4*11 = 44 >= 42

// No-LDS streaming SSIM. Each thread owns 2 adjacent columns (block of 256
// covers the full 512-col row). Per input row each thread loads its 14-float
// window (7 aligned float2 per input) straight from global -- the 7x lane
// overlap is served by L1/L2 (HBM was at 10% of peak in the LDS version, and
// that version was barrier/latency-bound: VALUBusy 59%, Occupancy 18.6%,
// 1e7 LDS bank-conflict cycles). No barriers in the main loop at all.
// Horizontal 11-tap conv of {p,t,p^2,t^2,pt} feeds an 11-deep register
// rolling buffer (statically indexed via unroll-by-11), then vertical 11-tap
// + SSIM once the window is full.
__global__ __launch_bounds__(256, 4)
void ssim_main(const float* __restrict__ Pg, const float* __restrict__ Tg,
               float* __restrict__ acc) {
    __shared__ float wavesum[4];

    const int t = threadIdx.x;
    const int R0 = blockIdx.x * BH;
    const size_t plane = (size_t)blockIdx.y * (IMG_H * IMG_W);
    const float* P = Pg + plane;
    const float* T = Tg + plane;

    // Gaussian weights: sigma=1.5, K=11, normalized (matches reference).
    // Compile-time constant args -> clang constant-folds expf; w[] becomes
    // literal constants, not registers.
    float w[11];
    {
        float s = 0.f;
#pragma unroll
        for (int k = 0; k < 11; ++k) {
            const float d = (float)(k - 5);
            w[k] = expf(-d * d / 4.5f);
            s += w[k];
        }
        const float inv = 1.0f / s;
#pragma unroll
        for (int k = 0; k < 11; ++k) w[k] *= inv;
    }

    // Rolling buffers: 5 maps x 2 cols x 11 rows. All indexing is static.
    float bP[2][11], bT[2][11], bPP[2][11], bTT[2][11], bPT[2][11];
    float ssum = 0.f;

    const int cbase = 2 * t - 6;   // leftmost col of this thread's 14-wide window

    for (int j = 0; j < NCHUNK; ++j) {
#pragma unroll
        for (int s = 0; s < 11; ++s) {
            const int li = 11 * j + s;   // uniform across block
            if (li < ROWS_IN) {
                const int gr = R0 - 5 + li;

                // Load the 14-float window (8B-aligned float2s), cols
                // cbase .. cbase+13 = 2t-6 .. 2t+7. Zero outside the image.
                float p[14], q[14];
                if (gr >= 0 && gr < IMG_H) {   // block-uniform branch
                    const float* Pr = P + (size_t)gr * IMG_W;
                    const float* Tr = T + (size_t)gr * IMG_W;
#pragma unroll
                    for (int k = 0; k < 7; ++k) {
                        const int c = cbase + 2 * k;   // even -> float2 fully in or out
                        float2 a = {0.f, 0.f}, b = {0.f, 0.f};
                        if (c >= 0 && c < IMG_W) {     // divergent only in edge lanes
                            a = *(const float2*)(Pr + c);
                            b = *(const float2*)(Tr + c);
                        }
                        p[2 * k] = a.x; p[2 * k + 1] = a.y;
                        q[2 * k] = b.x; q[2 * k + 1] = b.y;
                    }
                } else {
#pragma unroll
                    for (int k = 0; k < 14; ++k) { p[k] = 0.f; q[k] = 0.f; }
                }

                // Horizontal 11-tap conv of 5 maps for both columns.
                // Window for col0 (c=2t): indices 1..11; col1: 2..12.
                float h00 = 0, h01 = 0, h02 = 0, h03 = 0, h04 = 0;
                float h10 = 0, h11 = 0, h12 = 0, h13 = 0, h14 = 0;
#pragma unroll
                for (int i = 1; i <= 12; ++i) {
                    const float ppv = p[i] * p[i];
                    const float ttv = q[i] * q[i];
                    const float ptv = p[i] * q[i];
                    if (i <= 11) {
                        const float wk = w[i - 1];
                        h00 = fmaf(wk, p[i], h00);
                        h01 = fmaf(wk, q[i], h01);
                        h02 = fmaf(wk, ppv, h02);
                        h03 = fmaf(wk, ttv, h03);
                        h04 = fmaf(wk, ptv, h04);
                    }
                    if (i >= 2) {
                        const float wk = w[i - 2];
                        h10 = fmaf(wk, p[i], h10);
                        h11 = fmaf(wk, q[i], h11);
                        h12 = fmaf(wk, ppv, h12);
                        h13 = fmaf(wk, ttv, h13);
                        h14 = fmaf(wk, ptv, h14);
                    }
                }
                bP[0][s] = h00; bT[0][s] = h01; bPP[0][s] = h02; bTT[0][s] = h03; bPT[0][s] = h04;
                bP[1][s] = h10; bT[1][s] = h11; bPP[1][s] = h12; bTT[1][s] = h13; bPT[1][s] = h14;

                // Vertical 11-tap + SSIM once the window is full.
                if (li >= 10) {
#pragma unroll
                    for (int c = 0; c < 2; ++c) {
                        float mx = 0, my = 0, vxx = 0, vyy = 0, vxy = 0;
#pragma unroll
                        for (int k = 0; k < 11; ++k) {
                            const int sl = (s + 1 + k) % 11;  // compile-time
                            const float wk = w[k];
                            mx  = fmaf(wk, bP[c][sl],  mx);
                            my  = fmaf(wk, bT[c][sl],  my);
                            vxx = fmaf(wk, bPP[c][sl], vxx);
                            vyy = fmaf(wk, bTT[c][sl], vyy);
                            vxy = fmaf(wk, bPT[c][sl], vxy);
                        }
                        const float C1 = 4.0e-4f;   // (0.01*2)^2
                        const float C2 = 3.6e-3f;   // (0.03*2)^2
                        const float mxx = mx * mx, myy = my * my, mxy = mx * my;
                        const float sx = fmaxf(vxx - mxx, 0.f);
                        const float sy = fmaxf(vyy - myy, 0.f);
                        const float sxy = vxy - mxy;
                        const float num = fmaf(2.f, mxy, C1) * fmaf(2.f, sxy, C2);
                        const float den = (mxx + myy + C1) * (sx + sy + C2);
                        // rcp + one Newton-Raphson step: ~1 ulp at +2 FMA cost.
                        float r = __builtin_amdgcn_rcpf(den);
                        r = r * fmaf(-den, r, 2.0f);
                        ssum += num * r;
                    }
                }
            }
        }
    }

    // Reduce: wave shuffle -> per-wave LDS -> one atomic per block.
#pragma unroll
    for (int off = 32; off > 0; off >>= 1) ssum += __shfl_down(ssum, off);
    if ((t & 63) == 0) wavesum[t >> 6] = ssum;
    __syncthreads();
    if (t == 0) {
        atomicAdd(acc, wavesum[0] + wavesum[1] + wavesum[2] + wavesum[3]);
    }
}

__global__ void ssim_final(const float* __restrict__ acc, float* __restrict__ out) {
    out[0] = 1.0f - acc[0] / 25165824.0f;  // 32*3*512*512
}

extern "C" void kernel_launch(void* const* d_in, const int* in_sizes, int n_in,
                              void* d_out, int out_size, void* d_ws, size_t ws_size,
                              hipStream_t stream) {
    const float* pred = (const float*)d_in[0];
    const float* targ = (const float*)d_in[1];
    float* acc = (float*)d_ws;

    hipMemsetAsync(d_ws, 0, sizeof(float), stream);  // d_ws is re-poisoned 0xAA
    dim3 grid(NBANDS, NIMG);
    ssim_main<<<grid, 256, 0, stream>>>(pred, targ, acc);
    ssim_final<<<1, 1, 0, stream>>>(acc, (float*)d_out);
}

// Round 8
// 392.524 us; speedup vs baseline: 1.9217x; 1.9217x over previous
//
#include <hip/hip_runtime.h>
#include <math.h>

#define IMG_H 512
#define IMG_W 512
#define NIMG 96            // 32 * 3
#define BH 32              // output rows per band
#define NBANDS 16          // 512 / 32
#define ROWS_IN (BH + 10)  // 42 streamed input rows per band
#define NCHUNK 4           // 4*11 = 44 >= 42

// No-LDS streaming SSIM. Each thread owns 2 adjacent columns (block of 256
// covers the full 512-col row). Per input row each thread loads its 14-float
// window (7 aligned float2 per input) straight from global -- the 7x lane
// overlap is served by L1/L2. No barriers in the main loop.
//
// ROUND-6 LESSON (counters): __launch_bounds__(256,4) capped VGPR at 128,
// the ~160-float live set spilled to scratch (VGPR=64, WRITE_SIZE=288MB,
// FETCH=746MB, dur 650us). Bounds (256,2) caps at 256 VGPR: no spill,
// 2 waves/SIMD, ILP hides L1/L2 latency.
__global__ __launch_bounds__(256, 2)
void ssim_main(const float* __restrict__ Pg, const float* __restrict__ Tg,
               float* __restrict__ acc) {
    __shared__ float wavesum[4];

    const int t = threadIdx.x;
    const int R0 = blockIdx.x * BH;
    const size_t plane = (size_t)blockIdx.y * (IMG_H * IMG_W);
    const float* P = Pg + plane;
    const float* T = Tg + plane;

    // Gaussian weights: sigma=1.5, K=11, normalized (matches reference).
    // Compile-time constant args -> clang constant-folds expf; w[] becomes
    // literal constants, not registers.
    float w[11];
    {
        float s = 0.f;
#pragma unroll
        for (int k = 0; k < 11; ++k) {
            const float d = (float)(k - 5);
            w[k] = expf(-d * d / 4.5f);
            s += w[k];
        }
        const float inv = 1.0f / s;
#pragma unroll
        for (int k = 0; k < 11; ++k) w[k] *= inv;
    }

    // Rolling buffers: 5 maps x 2 cols x 11 rows. All indexing is static.
    float bP[2][11], bT[2][11], bPP[2][11], bTT[2][11], bPT[2][11];
    float ssum = 0.f;

    const int cbase = 2 * t - 6;   // leftmost col of this thread's 14-wide window

    for (int j = 0; j < NCHUNK; ++j) {
#pragma unroll
        for (int s = 0; s < 11; ++s) {
            const int li = 11 * j + s;   // uniform across block
            if (li < ROWS_IN) {
                const int gr = R0 - 5 + li;

                // Load the 14-float window (8B-aligned float2s), cols
                // cbase .. cbase+13 = 2t-6 .. 2t+7. Zero outside the image.
                float p[14], q[14];
                if (gr >= 0 && gr < IMG_H) {   // block-uniform branch
                    const float* Pr = P + (size_t)gr * IMG_W;
                    const float* Tr = T + (size_t)gr * IMG_W;
#pragma unroll
                    for (int k = 0; k < 7; ++k) {
                        const int c = cbase + 2 * k;   // even -> float2 fully in or out
                        float2 a = {0.f, 0.f}, b = {0.f, 0.f};
                        if (c >= 0 && c < IMG_W) {     // divergent only in edge lanes
                            a = *(const float2*)(Pr + c);
                            b = *(const float2*)(Tr + c);
                        }
                        p[2 * k] = a.x; p[2 * k + 1] = a.y;
                        q[2 * k] = b.x; q[2 * k + 1] = b.y;
                    }
                } else {
#pragma unroll
                    for (int k = 0; k < 14; ++k) { p[k] = 0.f; q[k] = 0.f; }
                }

                // Horizontal 11-tap conv of 5 maps for both columns.
                // Window for col0 (c=2t): indices 1..11; col1: 2..12.
                float h00 = 0, h01 = 0, h02 = 0, h03 = 0, h04 = 0;
                float h10 = 0, h11 = 0, h12 = 0, h13 = 0, h14 = 0;
#pragma unroll
                for (int i = 1; i <= 12; ++i) {
                    const float ppv = p[i] * p[i];
                    const float ttv = q[i] * q[i];
                    const float ptv = p[i] * q[i];
                    if (i <= 11) {
                        const float wk = w[i - 1];
                        h00 = fmaf(wk, p[i], h00);
                        h01 = fmaf(wk, q[i], h01);
                        h02 = fmaf(wk, ppv, h02);
                        h03 = fmaf(wk, ttv, h03);
                        h04 = fmaf(wk, ptv, h04);
                    }
                    if (i >= 2) {
                        const float wk = w[i - 2];
                        h10 = fmaf(wk, p[i], h10);
                        h11 = fmaf(wk, q[i], h11);
                        h12 = fmaf(wk, ppv, h12);
                        h13 = fmaf(wk, ttv, h13);
                        h14 = fmaf(wk, ptv, h14);
                    }
                }
                bP[0][s] = h00; bT[0][s] = h01; bPP[0][s] = h02; bTT[0][s] = h03; bPT[0][s] = h04;
                bP[1][s] = h10; bT[1][s] = h11; bPP[1][s] = h12; bTT[1][s] = h13; bPT[1][s] = h14;

                // Vertical 11-tap + SSIM once the window is full.
                if (li >= 10) {
#pragma unroll
                    for (int c = 0; c < 2; ++c) {
                        float mx = 0, my = 0, vxx = 0, vyy = 0, vxy = 0;
#pragma unroll
                        for (int k = 0; k < 11; ++k) {
                            const int sl = (s + 1 + k) % 11;  // compile-time
                            const float wk = w[k];
                            mx  = fmaf(wk, bP[c][sl],  mx);
                            my  = fmaf(wk, bT[c][sl],  my);
                            vxx = fmaf(wk, bPP[c][sl], vxx);
                            vyy = fmaf(wk, bTT[c][sl], vyy);
                            vxy = fmaf(wk, bPT[c][sl], vxy);
                        }
                        const float C1 = 4.0e-4f;   // (0.01*2)^2
                        const float C2 = 3.6e-3f;   // (0.03*2)^2
                        const float mxx = mx * mx, myy = my * my, mxy = mx * my;
                        const float sx = fmaxf(vxx - mxx, 0.f);
                        const float sy = fmaxf(vyy - myy, 0.f);
                        const float sxy = vxy - mxy;
                        const float num = fmaf(2.f, mxy, C1) * fmaf(2.f, sxy, C2);
                        const float den = (mxx + myy + C1) * (sx + sy + C2);
                        // rcp + one Newton-Raphson step: ~1 ulp at +2 FMA cost.
                        float r = __builtin_amdgcn_rcpf(den);
                        r = r * fmaf(-den, r, 2.0f);
                        ssum += num * r;
                    }
                }
            }
        }
    }

    // Reduce: wave shuffle -> per-wave LDS -> one atomic per block.
#pragma unroll
    for (int off = 32; off > 0; off >>= 1) ssum += __shfl_down(ssum, off);
    if ((t & 63) == 0) wavesum[t >> 6] = ssum;
    __syncthreads();
    if (t == 0) {
        atomicAdd(acc, wavesum[0] + wavesum[1] + wavesum[2] + wavesum[3]);
    }
}

__global__ void ssim_final(const float* __restrict__ acc, float* __restrict__ out) {
    out[0] = 1.0f - acc[0] / 25165824.0f;  // 32*3*512*512
}

extern "C" void kernel_launch(void* const* d_in, const int* in_sizes, int n_in,
                              void* d_out, int out_size, void* d_ws, size_t ws_size,
                              hipStream_t stream) {
    const float* pred = (const float*)d_in[0];
    const float* targ = (const float*)d_in[1];
    float* acc = (float*)d_ws;

    hipMemsetAsync(d_ws, 0, sizeof(float), stream);  // d_ws is re-poisoned 0xAA
    dim3 grid(NBANDS, NIMG);
    ssim_main<<<grid, 256, 0, stream>>>(pred, targ, acc);
    ssim_final<<<1, 1, 0, stream>>>(acc, (float*)d_out);
}

// Round 10
// 323.829 us; speedup vs baseline: 2.3294x; 1.2121x over previous
//
#include <hip/hip_runtime.h>
#include <math.h>

#define IMG_H 512
#define IMG_W 512
#define NIMG 96            // 32 * 3
#define BH 64              // output rows per band
#define NBANDS 8           // 512/64 -> 768 blocks = 3/CU exactly
#define ROWS_IN (BH + 10)  // 74 input rows per band
#define NPH 7              // 7 phases x 11 rows = 77 >= 74
#define EW 264             // de-interleaved array stride (words); 262 used

// Fused SSIM, phase-staged LDS version.
// Evidence trail:
//  r3 (LDS, 74 barriers):    142us, VALU 59%, 1e7 bank-conflict cyc -> barrier/conflict bound
//  r6 (noLDS, bounds(256,4)): 650us, VGPR=64 spill storm (WRITE 288MB)
//  r8 (noLDS, bounds(256,2)): 301us, VALU 39% -> L1-latency bound, no spill
// This version: LDS staging, but 11 rows/phase (2 barriers/phase, 14 total vs 74)
// and de-interleaved even/odd column arrays so every LDS access is stride-1
// b32 (2 lanes/bank = free) instead of stride-2-word float2 (4-way, even banks).
// 11-row phases keep the register rolling-buffer slot = r (compile-time).
__global__ __launch_bounds__(256, 2)
void ssim_main(const float* __restrict__ Pg, const float* __restrict__ Tg,
               float* __restrict__ acc) {
    // 4 arrays x 11 rows x 264 words x 4B = 46.5 KB -> 3 blocks/CU.
    __shared__ float sEP[11][EW], sOP[11][EW], sET[11][EW], sOT[11][EW];
    __shared__ float wavesum[4];

    const int t = threadIdx.x;
    const int R0 = blockIdx.x * BH;
    const size_t plane = (size_t)blockIdx.y * (IMG_H * IMG_W);
    const float* P = Pg + plane;
    const float* T = Tg + plane;

    // Gaussian weights: sigma=1.5, K=11, normalized (constant-folded expf).
    float w[11];
    {
        float s = 0.f;
#pragma unroll
        for (int k = 0; k < 11; ++k) {
            const float d = (float)(k - 5);
            w[k] = expf(-d * d / 4.5f);
            s += w[k];
        }
        const float inv = 1.0f / s;
#pragma unroll
        for (int k = 0; k < 11; ++k) w[k] *= inv;
    }

    // Rolling buffers: 5 maps x 2 cols x 11 rows; slot index is ALWAYS the
    // static phase-row r (11-row phases), so no dynamic register indexing.
    float bP[2][11], bT[2][11], bPP[2][11], bTT[2][11], bPT[2][11];
    float ssum = 0.f;

    for (int j = 0; j < NPH; ++j) {
        __syncthreads();   // previous phase's compute done -> LDS reusable

        // ---- Stage 11 rows (22 float2 global loads issued back-to-back) ----
#pragma unroll
        for (int r = 0; r < 11; ++r) {
            const int li = 11 * j + r;
            if (li < ROWS_IN) {                 // uniform
                const int gr = R0 - 5 + li;
                float2 a = {0.f, 0.f}, b = {0.f, 0.f};
                if (gr >= 0 && gr < IMG_H) {    // uniform
                    a = *(const float2*)(P + (size_t)gr * IMG_W + 2 * t);
                    b = *(const float2*)(T + (size_t)gr * IMG_W + 2 * t);
                }
                sEP[r][3 + t] = a.x;  sOP[r][3 + t] = a.y;
                sET[r][3 + t] = b.x;  sOT[r][3 + t] = b.y;
            }
        }
        // Halo zeros: even/odd col indices -3..-1 -> arr 0..2, 256..258 -> 259..261.
        if (t < 6) {
            const int idx = (t < 3) ? t : (256 + t);
#pragma unroll
            for (int r = 0; r < 11; ++r) {
                sEP[r][idx] = 0.f; sOP[r][idx] = 0.f;
                sET[r][idx] = 0.f; sOT[r][idx] = 0.f;
            }
        }
        __syncthreads();   // staged data visible

        // ---- Compute 11 rows ----
#pragma unroll
        for (int r = 0; r < 11; ++r) {
            const int li = 11 * j + r;
            if (li < ROWS_IN) {                 // uniform
                // Window cols 2t-6 .. 2t+7: p[2m]=E[t+m], p[2m+1]=O[t+m].
                float p[14], q[14];
#pragma unroll
                for (int m = 0; m < 7; ++m) {
                    p[2 * m]     = sEP[r][t + m];
                    p[2 * m + 1] = sOP[r][t + m];
                    q[2 * m]     = sET[r][t + m];
                    q[2 * m + 1] = sOT[r][t + m];
                }

                // Horizontal 11-tap conv of {p,t,p2,t2,pt} for both columns.
                float h00 = 0, h01 = 0, h02 = 0, h03 = 0, h04 = 0;
                float h10 = 0, h11 = 0, h12 = 0, h13 = 0, h14 = 0;
#pragma unroll
                for (int i = 1; i <= 12; ++i) {
                    const float ppv = p[i] * p[i];
                    const float ttv = q[i] * q[i];
                    const float ptv = p[i] * q[i];
                    if (i <= 11) {
                        const float wk = w[i - 1];
                        h00 = fmaf(wk, p[i], h00);
                        h01 = fmaf(wk, q[i], h01);
                        h02 = fmaf(wk, ppv, h02);
                        h03 = fmaf(wk, ttv, h03);
                        h04 = fmaf(wk, ptv, h04);
                    }
                    if (i >= 2) {
                        const float wk = w[i - 2];
                        h10 = fmaf(wk, p[i], h10);
                        h11 = fmaf(wk, q[i], h11);
                        h12 = fmaf(wk, ppv, h12);
                        h13 = fmaf(wk, ttv, h13);
                        h14 = fmaf(wk, ptv, h14);
                    }
                }
                bP[0][r] = h00; bT[0][r] = h01; bPP[0][r] = h02; bTT[0][r] = h03; bPT[0][r] = h04;
                bP[1][r] = h10; bT[1][r] = h11; bPP[1][r] = h12; bTT[1][r] = h13; bPT[1][r] = h14;

                // Vertical 11-tap + SSIM once 11 rows are live.
                if (li >= 10) {
#pragma unroll
                    for (int c = 0; c < 2; ++c) {
                        float mx = 0, my = 0, vxx = 0, vyy = 0, vxy = 0;
#pragma unroll
                        for (int k = 0; k < 11; ++k) {
                            const int sl = (r + 1 + k) % 11;  // compile-time
                            const float wk = w[k];
                            mx  = fmaf(wk, bP[c][sl],  mx);
                            my  = fmaf(wk, bT[c][sl],  my);
                            vxx = fmaf(wk, bPP[c][sl], vxx);
                            vyy = fmaf(wk, bTT[c][sl], vyy);
                            vxy = fmaf(wk, bPT[c][sl], vxy);
                        }
                        const float C1 = 4.0e-4f;   // (0.01*2)^2
                        const float C2 = 3.6e-3f;   // (0.03*2)^2
                        const float mxx = mx * mx, myy = my * my, mxy = mx * my;
                        const float sx = fmaxf(vxx - mxx, 0.f);
                        const float sy = fmaxf(vyy - myy, 0.f);
                        const float sxy = vxy - mxy;
                        const float num = fmaf(2.f, mxy, C1) * fmaf(2.f, sxy, C2);
                        const float den = (mxx + myy + C1) * (sx + sy + C2);
                        // rcp + one Newton-Raphson step (~1 ulp).
                        float rr = __builtin_amdgcn_rcpf(den);
                        rr = rr * fmaf(-den, rr, 2.0f);
                        ssum += num * rr;
                    }
                }
            }
        }
    }

    // Reduce: wave shuffle -> per-wave LDS -> one atomic per block.
#pragma unroll
    for (int off = 32; off > 0; off >>= 1) ssum += __shfl_down(ssum, off);
    if ((t & 63) == 0) wavesum[t >> 6] = ssum;
    __syncthreads();
    if (t == 0) {
        atomicAdd(acc, wavesum[0] + wavesum[1] + wavesum[2] + wavesum[3]);
    }
}

__global__ void ssim_final(const float* __restrict__ acc, float* __restrict__ out) {
    out[0] = 1.0f - acc[0] / 25165824.0f;  // 32*3*512*512
}

extern "C" void kernel_launch(void* const* d_in, const int* in_sizes, int n_in,
                              void* d_out, int out_size, void* d_ws, size_t ws_size,
                              hipStream_t stream) {
    const float* pred = (const float*)d_in[0];
    const float* targ = (const float*)d_in[1];
    float* acc = (float*)d_ws;

    hipMemsetAsync(d_ws, 0, sizeof(float), stream);  // d_ws is re-poisoned 0xAA
    dim3 grid(NBANDS, NIMG);
    ssim_main<<<grid, 256, 0, stream>>>(pred, targ, acc);
    ssim_final<<<1, 1, 0, stream>>>(acc, (float*)d_out);
}